// Round 10
// baseline (354.292 us; speedup 1.0000x reference)
//
#include <hip/hip_runtime.h>

#define NNODES 8000
#define MPAD   8192          // 32 * 256 (for the 256x256 GEMM1 tile)
#define NEDGES 40000
#define ETOT   (NEDGES + NNODES)   // 48000 with self loops
#define DIN    1024
#define NH     3
#define CH     1024
#define HC     (NH * CH)           // 3072
#define NTOT   (2 * HC)            // 6144 fused xl||xr
#define NCLS   460
#define NCLS_P 512
#define NEG    0.2f

typedef _Float16 h8 __attribute__((ext_vector_type(8)));
typedef _Float16 h4v __attribute__((ext_vector_type(4)));
typedef float    f4 __attribute__((ext_vector_type(4)));

// async global->LDS, 16B per lane; dest = wave-uniform base + lane*16 (m104)
#define GLOAD16(g, l) \
    __builtin_amdgcn_global_load_lds((const __attribute__((address_space(1))) void*)(g), \
                                     (__attribute__((address_space(3))) void*)(l), 16, 0, 0)

// ---------- fp32 -> fp16 convert with row padding ----------
__global__ __launch_bounds__(256)
void fp16_pad_convert(const float* __restrict__ in, _Float16* __restrict__ out,
                      int rows_in, int rows_out, int cols)
{
    size_t i4 = (size_t)blockIdx.x * 256 + threadIdx.x;
    size_t tot = ((size_t)rows_out * cols) >> 2;
    if (i4 >= tot) return;
    size_t e = i4 << 2;
    int row = (int)(e / cols);
    float vx = 0.f, vy = 0.f, vz = 0.f, vw = 0.f;
    if (row < rows_in) {
        float4 v = *(const float4*)(in + e);
        vx = v.x; vy = v.y; vz = v.z; vw = v.w;
    }
    h4v o = { (_Float16)vx, (_Float16)vy, (_Float16)vz, (_Float16)vw };
    *(h4v*)(out + e) = o;
}

// ---------- 3 transposes in one launch (z selects matrix) ----------
// z=0: Wl[1024][3072] -> BtW rows 0..3071 ; z=1: Wr -> BtW rows 3072..6143
// z=2: Wf[1024][460]  -> Wft rows 0..511 (zero-padded cols)
__global__ __launch_bounds__(256)
void transpose3(const float* __restrict__ Wl, const float* __restrict__ Wr,
                const float* __restrict__ Wf, _Float16* __restrict__ BtW,
                _Float16* __restrict__ Wft)
{
    const int z = blockIdx.z;
    const float* W;
    _Float16* out;
    int Ncols, rowOff;
    if (z == 0)      { W = Wl; out = BtW; Ncols = HC;   rowOff = 0;  }
    else if (z == 1) { W = Wr; out = BtW; Ncols = HC;   rowOff = HC; }
    else             { W = Wf; out = Wft; Ncols = NCLS; rowOff = 0;
                       if (blockIdx.x >= NCLS_P / 32) return; }

    __shared__ float tile[32][33];
    int n0 = blockIdx.x * 32, k0 = blockIdx.y * 32;
    int tx = threadIdx.x, ty = threadIdx.y;   // block (32,8)
    #pragma unroll
    for (int i = 0; i < 4; ++i) {
        int k = k0 + ty + i * 8;
        int n = n0 + tx;
        tile[ty + i * 8][tx] = (n < Ncols) ? W[(size_t)k * Ncols + n] : 0.f;
    }
    __syncthreads();
    #pragma unroll
    for (int i = 0; i < 4; ++i) {
        int n = n0 + ty + i * 8;
        int k = k0 + tx;
        out[(size_t)(rowOff + n) * DIN + k] = (_Float16)tile[tx][ty + i * 8];
    }
}

// ---------- biases + att->fp16 + csr histogram, one launch ----------
__global__ __launch_bounds__(256)
void prep_small(const float* __restrict__ bl, const float* __restrict__ br,
                const float* __restrict__ bf, const float* __restrict__ att,
                const int* __restrict__ ei,
                float* __restrict__ b1, float* __restrict__ b2,
                _Float16* __restrict__ atth, int* __restrict__ cnt)
{
    int i = blockIdx.x * 256 + threadIdx.x;
    if (i < HC) { b1[i] = bl[i]; b1[HC + i] = br[i]; atth[i] = (_Float16)att[i]; }
    if (i < NCLS_P) b2[i] = (i < NCLS) ? bf[i] : 0.f;
    if (i < ETOT) {
        int dst = (i < NEDGES) ? ei[2 * i + 1] : (i - NEDGES);
        atomicAdd(&cnt[dst], 1);
    }
}

// ---------- CSR scan / fill ----------
__global__ __launch_bounds__(1024)
void csr_scan(const int* __restrict__ cnt, int* __restrict__ rofs)
{
    __shared__ int s[1024];
    int t = threadIdx.x;
    int base = t * 8;
    int local[8];
    int sum = 0;
    #pragma unroll
    for (int i = 0; i < 8; ++i) {
        local[i] = sum;
        sum += (base + i < NNODES) ? cnt[base + i] : 0;
    }
    s[t] = sum;
    __syncthreads();
    for (int off = 1; off < 1024; off <<= 1) {
        int v = (t >= off) ? s[t - off] : 0;
        __syncthreads();
        if (t >= off) s[t] += v;
        __syncthreads();
    }
    int pre = (t > 0) ? s[t - 1] : 0;
    #pragma unroll
    for (int i = 0; i < 8; ++i)
        if (base + i < NNODES) rofs[base + i] = pre + local[i];
}

__global__ __launch_bounds__(256)
void csr_fill(const int* __restrict__ ei, const int* __restrict__ rofs,
              int* __restrict__ cursor, int* __restrict__ csr_src)
{
    int e = blockIdx.x * 256 + threadIdx.x;
    if (e >= ETOT) return;
    int src, dst;
    if (e < NEDGES) { src = ei[2 * e]; dst = ei[2 * e + 1]; }
    else            { src = dst = e - NEDGES; }
    int pos = rofs[dst] + atomicAdd(&cursor[dst], 1);
    csr_src[pos] = src;
}

// ---------- 256x256 8-phase fp16 MFMA GEMM (T2+T3+T4+T5) — unchanged from R9 ----------
__global__ __launch_bounds__(512, 2)
void gemm256_f16(const _Float16* __restrict__ A, const _Float16* __restrict__ Bt,
                 const float* __restrict__ biasN, _Float16* __restrict__ C16,
                 int N, int K)
{
    __shared__ __align__(16) _Float16 lds[65536];   // [buf]{A[256][64] | B[256][64]}

    int nwg = gridDim.x;
    int orig = blockIdx.x;
    int cpx = nwg >> 3;
    int wg = (orig & 7) * cpx + (orig >> 3);
    int nbx = N >> 8;
    int bm = wg / nbx, bn = wg - bm * nbx;
    int m0 = bm << 8, n0 = bn << 8;

    const int t = threadIdx.x;
    const int lane = t & 63;
    const int w = t >> 6;
    const int wm = w >> 2;
    const int wn = w & 3;

    const int sRow   = lane >> 3;
    const int sColSw = (((lane & 7) ^ sRow) << 3);
    const int seg0   = w << 1;

    const int l15 = lane & 15;

    f4 acc[8][4];
    f4 zero = { 0.f, 0.f, 0.f, 0.f };
    #pragma unroll
    for (int i = 0; i < 8; ++i)
        #pragma unroll
        for (int j = 0; j < 4; ++j) acc[i][j] = zero;

    auto STAGE_A = [&](int kt, int h, int b) {
        const _Float16* src = A + (size_t)(m0 + h * 128 + seg0 * 8 + sRow) * K + kt * 64 + sColSw;
        int dst = b * 32768 + h * 8192 + seg0 * 512;
        GLOAD16(src, &lds[dst]);
        GLOAD16(src + (size_t)8 * K, &lds[dst + 512]);
    };
    auto STAGE_B = [&](int kt, int h, int b) {
        const _Float16* src = Bt + (size_t)(n0 + h * 128 + seg0 * 8 + sRow) * K + kt * 64 + sColSw;
        int dst = b * 32768 + 16384 + h * 8192 + seg0 * 512;
        GLOAD16(src, &lds[dst]);
        GLOAD16(src + (size_t)8 * K, &lds[dst + 512]);
    };

    h8 bfr[4][2];
    const int aBase = wm * 128 + l15;
    const int bBase = wn * 64 + l15;

#define SWC(ks2) (((((ks2) * 4 + (lane >> 4)) ^ (l15 & 7)) << 3))
#define DS_A(fi, ks2, q, b) (*(const h8*)&lds[(b)*32768 + (aBase + (q)*32 + (fi)*16)*64 + SWC(ks2)])
#define DS_B(nf, ks2, b)    (*(const h8*)&lds[(b)*32768 + 16384 + (bBase + (nf)*16)*64 + SWC(ks2)])

#define PHASE(b, q, STAGE_STMT, VMEND)                                                            \
    {                                                                                             \
        h8 a00 = DS_A(0, 0, q, b), a01 = DS_A(0, 1, q, b);                                        \
        h8 a10 = DS_A(1, 0, q, b), a11 = DS_A(1, 1, q, b);                                        \
        if ((q) == 0) {                                                                           \
            _Pragma("unroll")                                                                     \
            for (int nf = 0; nf < 4; ++nf) {                                                      \
                bfr[nf][0] = DS_B(nf, 0, b);                                                      \
                bfr[nf][1] = DS_B(nf, 1, b);                                                      \
            }                                                                                     \
        }                                                                                         \
        STAGE_STMT;                                                                               \
        __builtin_amdgcn_s_barrier();                                                             \
        asm volatile("s_waitcnt lgkmcnt(0)" ::: "memory");                                        \
        __builtin_amdgcn_sched_barrier(0);                                                        \
        __builtin_amdgcn_s_setprio(1);                                                            \
        _Pragma("unroll")                                                                         \
        for (int nf = 0; nf < 4; ++nf) {                                                          \
            acc[(q)*2+0][nf] = __builtin_amdgcn_mfma_f32_16x16x32_f16(a00, bfr[nf][0], acc[(q)*2+0][nf], 0, 0, 0); \
            acc[(q)*2+0][nf] = __builtin_amdgcn_mfma_f32_16x16x32_f16(a01, bfr[nf][1], acc[(q)*2+0][nf], 0, 0, 0); \
            acc[(q)*2+1][nf] = __builtin_amdgcn_mfma_f32_16x16x32_f16(a10, bfr[nf][0], acc[(q)*2+1][nf], 0, 0, 0); \
            acc[(q)*2+1][nf] = __builtin_amdgcn_mfma_f32_16x16x32_f16(a11, bfr[nf][1], acc[(q)*2+1][nf], 0, 0, 0); \
        }                                                                                         \
        __builtin_amdgcn_s_setprio(0);                                                            \
        if (VMEND) asm volatile("s_waitcnt vmcnt(4)" ::: "memory");                               \
        __builtin_amdgcn_s_barrier();                                                             \
    }

    STAGE_A(0, 0, 0); STAGE_A(0, 1, 0);
    STAGE_B(0, 0, 0); STAGE_B(0, 1, 0);
    STAGE_B(1, 0, 1); STAGE_B(1, 1, 1);
    asm volatile("s_waitcnt vmcnt(4)" ::: "memory");
    __builtin_amdgcn_s_barrier();

    const int NKT = K >> 6;
    for (int kt = 0; kt < NKT; kt += 2) {
        PHASE(0, 0, STAGE_A(kt + 1, 0, 1), false);
        PHASE(0, 1, STAGE_A(kt + 1, 1, 1), false);
        PHASE(0, 2, STAGE_B(kt + 2, 0, 0), false);
        PHASE(0, 3, STAGE_B(kt + 2, 1, 0), true);
        PHASE(1, 0, STAGE_A(kt + 2, 0, 0), false);
        PHASE(1, 1, STAGE_A(kt + 2, 1, 0), false);
        PHASE(1, 2, STAGE_B(kt + 3, 0, 1), false);
        PHASE(1, 3, STAGE_B(kt + 3, 1, 1), true);
    }

#undef PHASE
#undef DS_A
#undef DS_B
#undef SWC

    #pragma unroll
    for (int mf = 0; mf < 8; ++mf) {
        int row0 = m0 + wm * 128 + mf * 16 + ((lane >> 4) << 2);
        #pragma unroll
        for (int nf = 0; nf < 4; ++nf) {
            int col = n0 + wn * 64 + nf * 16 + l15;
            float bb = biasN[col];
            #pragma unroll
            for (int rg = 0; rg < 4; ++rg)
                C16[(size_t)(row0 + rg) * N + col] = (_Float16)(acc[mf][nf][rg] + bb);
        }
    }
}

// ---------- GEMM2 + fused row softmax: block = 64 rows x full 512 cols ----------
// 512 thr = 8 waves (2M x 4N); BK=32 gload_lds staging; epilogue stages logits
// to LDS (stride 521) in two 32-row halves, softmax, writes d_out directly.
__global__ __launch_bounds__(512, 2)
void gemm2_sm(const _Float16* __restrict__ A, const _Float16* __restrict__ Bt,
              const float* __restrict__ biasN, float* __restrict__ out)
{
    __shared__ __align__(16) char smem[66816];
    _Float16* sAB  = (_Float16*)smem;   // A[64][32] elems 0..2047, B[512][32] elems 2048..18431
    float*    sLog = (float*)smem;      // [32][521] after K-loop

    const int bm = blockIdx.x;
    const int m0 = bm << 6;

    const int t = threadIdx.x;
    const int lane = t & 63;
    const int w = t >> 6;
    const int wm = w >> 2;              // 0..1 (32-row half)
    const int wn = w & 3;               // 0..3 (128-col quarter)
    const int l15 = lane & 15;
    const int ks8 = (lane >> 4) << 3;

    f4 acc[2][8];
    f4 zero = { 0.f, 0.f, 0.f, 0.f };
    #pragma unroll
    for (int i = 0; i < 2; ++i)
        #pragma unroll
        for (int j = 0; j < 8; ++j) acc[i][j] = zero;

    const int sr = lane >> 2, sc = (lane & 3) << 3;   // 16 rows x 32 cols per gload
    const _Float16* gA = A  + (size_t)(m0 + w * 16 + sr) * DIN + sc;   // waves 0-3
    const _Float16* gB = Bt + (size_t)(w * 64 + sr) * DIN + sc;

    for (int s = 0; s < DIN / 32; ++s) {
        const int ko = s << 5;
        if (w < 4) GLOAD16(gA + ko, &sAB[w * 512]);
        #pragma unroll
        for (int j = 0; j < 4; ++j)
            GLOAD16(gB + (size_t)j * 16 * DIN + ko, &sAB[2048 + (w * 4 + j) * 512]);
        __syncthreads();
        h8 bh[8];
        #pragma unroll
        for (int nf = 0; nf < 8; ++nf)
            bh[nf] = *(const h8*)&sAB[2048 + (wn * 128 + nf * 16 + l15) * 32 + ks8];
        #pragma unroll
        for (int mi = 0; mi < 2; ++mi) {
            h8 ah = *(const h8*)&sAB[(wm * 32 + mi * 16 + l15) * 32 + ks8];
            #pragma unroll
            for (int nf = 0; nf < 8; ++nf)
                acc[mi][nf] = __builtin_amdgcn_mfma_f32_16x16x32_f16(ah, bh[nf], acc[mi][nf], 0, 0, 0);
        }
        __syncthreads();
    }

    // epilogue: two 32-row halves; logits -> LDS -> softmax -> d_out
    for (int hh = 0; hh < 2; ++hh) {
        if (wm == hh) {
            #pragma unroll
            for (int mi = 0; mi < 2; ++mi) {
                int lrow = mi * 16 + ((lane >> 4) << 2);   // 0..31 within half
                #pragma unroll
                for (int nf = 0; nf < 8; ++nf) {
                    int col = wn * 128 + nf * 16 + l15;
                    float b = biasN[col];
                    #pragma unroll
                    for (int rg = 0; rg < 4; ++rg)
                        sLog[(lrow + rg) * 521 + col] = acc[mi][nf][rg] + b;
                }
            }
        }
        __syncthreads();
        {
            int lrow = t >> 4;          // 0..31
            int s16  = t & 15;
            int grow = m0 + hh * 32 + lrow;
            float vbuf[32];
            float mx = -3.4e38f;
            #pragma unroll
            for (int k = 0; k < 32; ++k) {
                int col = s16 + (k << 4);
                float v = (col < NCLS) ? sLog[lrow * 521 + col] : -3.4e38f;
                vbuf[k] = v;
                mx = fmaxf(mx, v);
            }
            #pragma unroll
            for (int off = 8; off > 0; off >>= 1) mx = fmaxf(mx, __shfl_xor(mx, off));
            float sum = 0.f;
            #pragma unroll
            for (int k = 0; k < 32; ++k) {
                int col = s16 + (k << 4);
                float e = (col < NCLS) ? __expf(vbuf[k] - mx) : 0.f;
                vbuf[k] = e;
                sum += e;
            }
            #pragma unroll
            for (int off = 8; off > 0; off >>= 1) sum += __shfl_xor(sum, off);
            float inv = 1.f / sum;
            if (grow < NNODES) {
                #pragma unroll
                for (int k = 0; k < 32; ++k) {
                    int col = s16 + (k << 4);
                    if (col < NCLS) out[(size_t)grow * NCLS + col] = vbuf[k] * inv;
                }
            }
        }
        __syncthreads();
    }
}

// ---------- fused edge path: 3-wave block per dst, wave-per-head, 2-deep prefetch ----------
__global__ __launch_bounds__(192)
void edge_fused3(const _Float16* __restrict__ xlr, const int* __restrict__ rofs,
                 const int* __restrict__ cnt, const int* __restrict__ csr_src,
                 const _Float16* __restrict__ atth, const float* __restrict__ bias,
                 _Float16* __restrict__ o2h)
{
    __shared__ float comb[3 * CH];   // 12 KB

    const int dst = blockIdx.x;
    const int h   = threadIdx.x >> 6;    // wave = head
    const int l   = threadIdx.x & 63;
    const int cb0 = l << 3, cb1 = 512 + (l << 3);

    const _Float16* pr = xlr + (size_t)dst * NTOT + HC + h * CH;
    h8 xr0 = *(const h8*)(pr + cb0);
    h8 xr1 = *(const h8*)(pr + cb1);
    h8 at0 = *(const h8*)(atth + h * CH + cb0);
    h8 at1 = *(const h8*)(atth + h * CH + cb1);

    const int beg = rofs[dst];
    const int num = cnt[dst];

    float m = -3.4e38f, d = 0.f;
    float a0[8] = {}, a1[8] = {};

    // 2-deep pipeline: slots A (even i) and B (odd i)
    int srcA = csr_src[beg];
    const _Float16* pA = xlr + (size_t)srcA * NTOT + h * CH;
    h8 eA0 = *(const h8*)(pA + cb0), eA1 = *(const h8*)(pA + cb1);
    h8 eB0 = eA0, eB1 = eA1;
    if (num > 1) {
        int srcB = csr_src[beg + 1];
        const _Float16* pB = xlr + (size_t)srcB * NTOT + h * CH;
        eB0 = *(const h8*)(pB + cb0);
        eB1 = *(const h8*)(pB + cb1);
    }

    #pragma unroll 2
    for (int i = 0; i < num; ++i) {
        const bool odd = (i & 1) != 0;
        h8 xv0 = odd ? eB0 : eA0;
        h8 xv1 = odd ? eB1 : eA1;
        if (i + 2 < num) {
            int s2 = csr_src[beg + i + 2];
            const _Float16* p2 = xlr + (size_t)s2 * NTOT + h * CH;
            h8 n0 = *(const h8*)(p2 + cb0);
            h8 n1 = *(const h8*)(p2 + cb1);
            if (odd) { eB0 = n0; eB1 = n1; } else { eA0 = n0; eA1 = n1; }
        }
        float s = 0.f;
        #pragma unroll
        for (int j = 0; j < 8; ++j) {
            float z0 = (float)xv0[j] + (float)xr0[j];
            z0 = z0 > 0.f ? z0 : NEG * z0;
            s = fmaf((float)at0[j], z0, s);
            float z1 = (float)xv1[j] + (float)xr1[j];
            z1 = z1 > 0.f ? z1 : NEG * z1;
            s = fmaf((float)at1[j], z1, s);
        }
        #pragma unroll
        for (int off = 32; off > 0; off >>= 1) s += __shfl_xor(s, off);
        float nm = fmaxf(m, s);
        float rs = __expf(m - nm);              // first iter: exp(-big)=0
        float wt = __expf(s - nm);
        d = d * rs + wt;
        #pragma unroll
        for (int j = 0; j < 8; ++j) {
            a0[j] = fmaf(wt, (float)xv0[j], a0[j] * rs);
            a1[j] = fmaf(wt, (float)xv1[j], a1[j] * rs);
        }
        m = nm;
    }

    float inv = 1.f / (d + 1e-16f) * (1.f / 3.f);
    #pragma unroll
    for (int j = 0; j < 8; ++j) {
        comb[h * CH + cb0 + j] = a0[j] * inv;
        comb[h * CH + cb1 + j] = a1[j] * inv;
    }
    __syncthreads();

    if (threadIdx.x < 128) {
        int c = threadIdx.x << 3;
        h8 o;
        #pragma unroll
        for (int j = 0; j < 8; ++j) {
            float v = comb[c + j] + comb[CH + c + j] + comb[2 * CH + c + j] + bias[c + j];
            o[j] = (_Float16)v;
        }
        *(h8*)(o2h + (size_t)dst * CH + c) = o;
    }
}

extern "C" void kernel_launch(void* const* d_in, const int* in_sizes, int n_in,
                              void* d_out, int out_size, void* d_ws, size_t ws_size,
                              hipStream_t stream)
{
    (void)in_sizes; (void)n_in; (void)out_size; (void)ws_size;

    const float* x    = (const float*)d_in[0];
    const int*   ei   = (const int*)  d_in[1];
    const float* Wl   = (const float*)d_in[2];
    const float* bl   = (const float*)d_in[3];
    const float* Wr   = (const float*)d_in[4];
    const float* br   = (const float*)d_in[5];
    const float* att  = (const float*)d_in[6];
    const float* bias = (const float*)d_in[7];
    const float* Wf   = (const float*)d_in[8];
    const float* bf   = (const float*)d_in[9];

    char* base = (char*)d_ws;
    _Float16* xh      = (_Float16*)(base);                      // [8192][1024]   16,777,216
    _Float16* BtW     = (_Float16*)(base + 16777216);           // [6144][1024]   12,582,912
    _Float16* Wft     = (_Float16*)(base + 29360128);           // [512][1024]     1,048,576
    float*    biasC1  = (float*)   (base + 30408704);           // [6144]             24,576
    float*    biasC2  = (float*)   (base + 30433280);           // [512]               2,048
    _Float16* atth    = (_Float16*)(base + 30435328);           // [3072]              6,144
    int*      cnt     = (int*)     (base + 30441472);           // [8000]             32,000
    int*      cursor  = (int*)     (base + 30473472);           // [8000]             32,000
    int*      rofs    = (int*)     (base + 30505472);           // [8000]             32,000
    int*      csr_src = (int*)     (base + 30537472);           // [48000]           192,000
    _Float16* o2h     = (_Float16*)(base + 30729472);           // [8192][1024]   16,777,216
    _Float16* xlr     = (_Float16*)(base + 64283904);           // [8192][6144]  100,663,296

    // zero cnt | cursor (contiguous)
    hipMemsetAsync(cnt, 0, 64000, stream);

    fp16_pad_convert<<<(MPAD * DIN / 4 + 255) / 256, 256, 0, stream>>>(
        x, xh, NNODES, MPAD, DIN);

    transpose3<<<dim3(HC / 32, DIN / 32, 3), dim3(32, 8), 0, stream>>>(
        Wl, Wr, Wf, BtW, Wft);

    prep_small<<<(ETOT + 255) / 256, 256, 0, stream>>>(
        bl, br, bf, att, ei, biasC1, biasC2, atth, cnt);

    csr_scan<<<1, 1024, 0, stream>>>(cnt, rofs);
    csr_fill<<<(ETOT + 255) / 256, 256, 0, stream>>>(ei, rofs, cursor, csr_src);

    // GEMM1 fused (256^2 8-phase + T2 swizzle): xlr[8192][6144] fp16
    gemm256_f16<<<(MPAD / 256) * (NTOT / 256), 512, 0, stream>>>(
        xh, BtW, biasC1, xlr, NTOT, DIN);

    // fused edge path: 3-wave block per dst, wave-per-head, 2-deep prefetch
    edge_fused3<<<NNODES, 192, 0, stream>>>(xlr, rofs, cnt, csr_src, atth, bias, o2h);

    // GEMM2 + row softmax fused -> d_out
    gemm2_sm<<<MPAD / 64, 512, 0, stream>>>(o2h, Wft, biasC2, (float*)d_out);
}